// Round 5
// baseline (4239.263 us; speedup 1.0000x reference)
//
#include <hip/hip_runtime.h>

// Problem constants: B=32, S=1024, I=1024, H=1024, W is (H, I+H)
#define B_ 32
#define S_ 1024
#define H_ 1024
#define EXN (32 * 1024)   // u16 cells per parity buffer (32 batches x 1024 cols)

typedef float f32x4 __attribute__((ext_vector_type(4)));
typedef short bf16x8 __attribute__((ext_vector_type(8)));
typedef unsigned short u16;

__device__ __forceinline__ short f2bf(float f) {
  union { float f; unsigned u; } v; v.f = f;
  unsigned r = v.u + 0x7FFFu + ((v.u >> 16) & 1u);
  return (short)(r >> 16);
}

__device__ __forceinline__ void stg_coh_u16(u16* p, u16 v) {
  asm volatile("global_store_short %0, %1, off sc0 sc1"
               :: "v"(p), "v"(v) : "memory");
}
__device__ __forceinline__ void stg_coh_u32(unsigned* p, unsigned v) {
  asm volatile("global_store_dword %0, %1, off sc0 sc1"
               :: "v"(p), "v"(v) : "memory");
}

// ============================================================================
// Kernel 1: xz GEMM (R1-verified, unchanged).
//   C[m][n] = sum_k x[m][k] * W[n][1024+k] + bias[n] -> d_out in-place.
// ============================================================================
__global__ __launch_bounds__(256) void xz_gemm(
    const float* __restrict__ X, const float* __restrict__ W,
    const float* __restrict__ bias, float* __restrict__ C) {
  __shared__ short As[128][40];
  __shared__ short Bs[128][40];
  const int tid  = threadIdx.x;
  const int lane = tid & 63, wave = tid >> 6;
  const int m0 = blockIdx.y * 128, n0 = blockIdx.x * 128;
  const int wm = (wave >> 1) * 64, wn = (wave & 1) * 64;
  const int jl = lane & 15, kq = lane >> 4;
  const int sr = tid >> 2, skg = (tid & 3) * 8;

  f32x4 zero4 = {0.f, 0.f, 0.f, 0.f};
  f32x4 acc[4][4];
  #pragma unroll
  for (int mi = 0; mi < 4; ++mi)
    #pragma unroll
    for (int ni = 0; ni < 4; ++ni) acc[mi][ni] = zero4;

  for (int k0 = 0; k0 < 1024; k0 += 32) {
    #pragma unroll
    for (int rr = 0; rr < 2; ++rr) {
      int row = sr + rr * 64;
      const float* pa = X + (size_t)(m0 + row) * 1024 + k0 + skg;
      f32x4 a0 = *(const f32x4*)pa;
      f32x4 a1 = *(const f32x4*)(pa + 4);
      bf16x8 pk;
      #pragma unroll
      for (int e = 0; e < 4; ++e) { pk[e] = f2bf(a0[e]); pk[e + 4] = f2bf(a1[e]); }
      *(bf16x8*)&As[row][skg] = pk;
      const float* pb = W + (size_t)(n0 + row) * 2048 + 1024 + k0 + skg;
      f32x4 b0 = *(const f32x4*)pb;
      f32x4 b1 = *(const f32x4*)(pb + 4);
      bf16x8 qk;
      #pragma unroll
      for (int e = 0; e < 4; ++e) { qk[e] = f2bf(b0[e]); qk[e + 4] = f2bf(b1[e]); }
      *(bf16x8*)&Bs[row][skg] = qk;
    }
    __syncthreads();
    bf16x8 af[4], bfv[4];
    #pragma unroll
    for (int mi = 0; mi < 4; ++mi) af[mi] = *(const bf16x8*)&As[wm + mi * 16 + jl][kq * 8];
    #pragma unroll
    for (int ni = 0; ni < 4; ++ni) bfv[ni] = *(const bf16x8*)&Bs[wn + ni * 16 + jl][kq * 8];
    #pragma unroll
    for (int mi = 0; mi < 4; ++mi)
      #pragma unroll
      for (int ni = 0; ni < 4; ++ni)
        acc[mi][ni] = __builtin_amdgcn_mfma_f32_16x16x32_bf16(af[mi], bfv[ni], acc[mi][ni], 0, 0, 0);
    __syncthreads();
  }
  #pragma unroll
  for (int ni = 0; ni < 4; ++ni) {
    int col = n0 + wn + ni * 16 + jl;
    float bv = bias[col];
    #pragma unroll
    for (int mi = 0; mi < 4; ++mi) {
      int rbase = m0 + wm + mi * 16 + kq * 4;
      #pragma unroll
      for (int r = 0; r < 4; ++r)
        C[(size_t)(rbase + r) * 1024 + col] = acc[mi][ni][r] + bv;
    }
  }
}

// ============================================================================
// Kernel 2: 128 INDEPENDENT single-wave workgroups. wg = (bt, ct):
//   bt in {0,1} (16 batches), ct in [0,64) (16 z-cols). Wave computes the full
//   K=1024 for its 16x16 z-tile; Wh tile lives in 128 VGPRs. No LDS, no
//   __syncthreads, no cross-wave reduce. The two bt groups are independent.
//   Per step: poll 64 flags (1 dword/lane) -> 32 coherent dwordx4 A-loads ->
//   32 MFMA (4 acc chains) -> per-lane gates on 4 owned cells -> 4 bf16
//   stores -> vmcnt ack -> flag. WAR on parity buffer: publishing t+2
//   requires having consumed t+1 from all 64 same-bt producers, which implies
//   their reads of parity (t) completed.
// ============================================================================
__global__ __launch_bounds__(64) void lstm_rec(
    const float* __restrict__ W, const float* __restrict__ h0,
    const float* __restrict__ c0, float* __restrict__ out,
    u16* __restrict__ exch, unsigned* __restrict__ flags) {
  const int lane = threadIdx.x & 63;
  const int wg   = blockIdx.x;          // 0..127
  const int bt   = wg >> 6;             // batch-tile
  const int ct   = wg & 63;             // col-tile
  const int jl   = lane & 15, kq = lane >> 4;

  // --- Wh tile -> registers: B-frag[kk], rows ct*16+jl, k = kk*32+kq*8
  bf16x8 Bf[32];
  {
    const float* wrow = W + (size_t)(ct * 16 + jl) * 2048;   // Wh = W[:, :1024]
    #pragma unroll
    for (int kk = 0; kk < 32; ++kk) {
      const float* p = wrow + kk * 32 + kq * 8;
      f32x4 a0 = *(const f32x4*)p;
      f32x4 a1 = *(const f32x4*)(p + 4);
      bf16x8 pk;
      #pragma unroll
      for (int e = 0; e < 4; ++e) { pk[e] = f2bf(a0[e]); pk[e + 4] = f2bf(a1[e]); }
      Bf[kk] = pk;
    }
  }

  // --- owned cells: (batch = b0+r, col), r = 0..3  (D-frag layout m89/m91)
  const int b0  = bt * 16 + kq * 4;
  const int col = ct * 16 + jl;
  float c[4], h[4];
  #pragma unroll
  for (int r = 0; r < 4; ++r) {
    c[r] = c0[(b0 + r) * 1024 + col];
    h[r] = h0[(b0 + r) * 1024 + col];
  }
  // publish version 0 (h0) into parity 0
  #pragma unroll
  for (int r = 0; r < 4; ++r)
    stg_coh_u16(exch + (b0 + r) * 1024 + col, (u16)f2bf(h[r]));
  asm volatile("s_waitcnt vmcnt(0)" ::: "memory");
  unsigned* myflag = flags + wg;
  if (lane == 0) stg_coh_u32(myflag, 1u);

  const u16* aB = exch + (size_t)(bt * 16 + jl) * 1024 + kq * 8;
  const unsigned* fptr = flags + (bt << 6) + lane;   // lane <-> producer ct

  for (int t = 0; t < S_; ++t) {
    // ---- xz loads (plain cached; stable until our own h store this step)
    float xz[4];
    #pragma unroll
    for (int r = 0; r < 4; ++r)
      xz[r] = out[((size_t)(b0 + r) * S_ + t) * H_ + col];

    // ---- poll: all 64 same-bt producers at version >= t+1
    unsigned fv;
    for (;;) {
      asm volatile("global_load_dword %0, %1, off sc0 sc1"
                   : "=v"(fv) : "v"(fptr) : "memory");
      asm volatile("s_waitcnt vmcnt(0)" ::: "memory");
      if (__all(fv > (unsigned)t)) break;
      __builtin_amdgcn_s_sleep(1);
    }
    __builtin_amdgcn_sched_barrier(0);

    // ---- 32 coherent A-frag loads from parity t&1 (one base, literal offs)
    const u16* src = aB + (size_t)(t & 1) * EXN;
    bf16x8 A[32];
#define LDA(K, OFF) asm volatile( \
    "global_load_dwordx4 %0, %1, off offset:" OFF " sc0 sc1" \
    : "=v"(A[K]) : "v"(src) : "memory")
    LDA(0, "0");     LDA(1, "64");    LDA(2, "128");   LDA(3, "192");
    LDA(4, "256");   LDA(5, "320");   LDA(6, "384");   LDA(7, "448");
    LDA(8, "512");   LDA(9, "576");   LDA(10, "640");  LDA(11, "704");
    LDA(12, "768");  LDA(13, "832");  LDA(14, "896");  LDA(15, "960");
    LDA(16, "1024"); LDA(17, "1088"); LDA(18, "1152"); LDA(19, "1216");
    LDA(20, "1280"); LDA(21, "1344"); LDA(22, "1408"); LDA(23, "1472");
    LDA(24, "1536"); LDA(25, "1600"); LDA(26, "1664"); LDA(27, "1728");
    LDA(28, "1792"); LDA(29, "1856"); LDA(30, "1920"); LDA(31, "1984");
#undef LDA
    asm volatile("s_waitcnt vmcnt(0)" ::: "memory");
    __builtin_amdgcn_sched_barrier(0);

    // ---- 32 MFMA, 4 accumulator chains of 8
    f32x4 acc[4];
    #pragma unroll
    for (int a = 0; a < 4; ++a) acc[a] = (f32x4){0.f, 0.f, 0.f, 0.f};
    #pragma unroll
    for (int kk = 0; kk < 32; ++kk)
      acc[kk & 3] = __builtin_amdgcn_mfma_f32_16x16x32_bf16(A[kk], Bf[kk], acc[kk & 3], 0, 0, 0);

    // ---- gates on 4 owned cells; publish
    u16* dst = exch + (size_t)((t + 1) & 1) * EXN;
    #pragma unroll
    for (int r = 0; r < 4; ++r) {
      float z  = xz[r] + (acc[0][r] + acc[1][r]) + (acc[2][r] + acc[3][r]);
      float u  = __expf(-z);
      float u2 = u * u;
      float sg = __builtin_amdgcn_rcpf(1.f + u);                 // sigmoid(z)
      float tz = (1.f - u2) * __builtin_amdgcn_rcpf(1.f + u2);   // tanh(z)
      c[r] = sg * (c[r] + tz);
      float v  = __expf(-2.f * c[r]);
      float tc = (1.f - v) * __builtin_amdgcn_rcpf(1.f + v);     // tanh(c)
      h[r] = sg * tc;
      out[((size_t)(b0 + r) * S_ + t) * H_ + col] = h[r];        // plain store
      stg_coh_u16(dst + (b0 + r) * 1024 + col, (u16)f2bf(h[r]));
    }
    asm volatile("s_waitcnt vmcnt(0)" ::: "memory");   // exch stores acked
    if (lane == 0) stg_coh_u32(myflag, (unsigned)(t + 2));
  }

  // ---- hn, cn
  const size_t OFS = (size_t)B_ * S_ * H_;
  #pragma unroll
  for (int r = 0; r < 4; ++r) {
    out[OFS + (b0 + r) * 1024 + col] = h[r];
    out[OFS + (size_t)B_ * H_ + (b0 + r) * 1024 + col] = c[r];
  }
}

// ============================================================================
extern "C" void kernel_launch(void* const* d_in, const int* in_sizes, int n_in,
                              void* d_out, int out_size, void* d_ws, size_t ws_size,
                              hipStream_t stream) {
  const float* x    = (const float*)d_in[0];
  const float* h0   = (const float*)d_in[1];
  const float* c0   = (const float*)d_in[2];
  const float* W    = (const float*)d_in[3];
  const float* bias = (const float*)d_in[4];
  float* out = (float*)d_out;

  u16* exch = (u16*)d_ws;                         // 2 x 64 KB ping-pong (bf16)
  unsigned* flags = (unsigned*)((char*)d_ws + 2 * EXN * sizeof(u16));
  hipMemsetAsync(flags, 0, 128 * sizeof(unsigned), stream);

  xz_gemm<<<dim3(8, 256), 256, 0, stream>>>(x, W, bias, out);
  lstm_rec<<<dim3(128), 64, 0, stream>>>(W, h0, c0, out, exch, flags);
}

// Round 6
// 3016.706 us; speedup vs baseline: 1.4053x; 1.4053x over previous
//
#include <hip/hip_runtime.h>

// Problem constants: B=32, S=1024, I=1024, H=1024, W is (H, I+H)
#define B_ 32
#define S_ 1024
#define H_ 1024
#define NWG 64          // 2 batch-groups x 32 col-groups
#define EXN (32 * 1024) // one exchange buffer: 32 x 1024 bf16 cells

typedef float f32x4 __attribute__((ext_vector_type(4)));
typedef short bf16x8 __attribute__((ext_vector_type(8)));
typedef unsigned short u16;

__device__ __forceinline__ short f2bf(float f) {
  union { float f; unsigned u; } v; v.f = f;
  unsigned r = v.u + 0x7FFFu + ((v.u >> 16) & 1u);
  return (short)(r >> 16);
}

// Agent-scope (cross-XCD coherent, L3 coherence point) ops — sc1 only.
__device__ __forceinline__ void stg_coh_u16(u16* p, u16 v) {
  asm volatile("global_store_short %0, %1, off sc1" :: "v"(p), "v"(v) : "memory");
}
__device__ __forceinline__ void stg_coh_u32(unsigned* p, unsigned v) {
  asm volatile("global_store_dword %0, %1, off sc1" :: "v"(p), "v"(v) : "memory");
}

// ============================================================================
// Kernel 1: xz GEMM (R1-verified, unchanged).
//   C[m][n] = sum_k x[m][k] * W[n][1024+k] + bias[n] -> d_out in-place.
// ============================================================================
__global__ __launch_bounds__(256) void xz_gemm(
    const float* __restrict__ X, const float* __restrict__ W,
    const float* __restrict__ bias, float* __restrict__ C) {
  __shared__ short As[128][40];
  __shared__ short Bs[128][40];
  const int tid  = threadIdx.x;
  const int lane = tid & 63, wave = tid >> 6;
  const int m0 = blockIdx.y * 128, n0 = blockIdx.x * 128;
  const int wm = (wave >> 1) * 64, wn = (wave & 1) * 64;
  const int jl = lane & 15, kq = lane >> 4;
  const int sr = tid >> 2, skg = (tid & 3) * 8;

  f32x4 zero4 = {0.f, 0.f, 0.f, 0.f};
  f32x4 acc[4][4];
  #pragma unroll
  for (int mi = 0; mi < 4; ++mi)
    #pragma unroll
    for (int ni = 0; ni < 4; ++ni) acc[mi][ni] = zero4;

  for (int k0 = 0; k0 < 1024; k0 += 32) {
    #pragma unroll
    for (int rr = 0; rr < 2; ++rr) {
      int row = sr + rr * 64;
      const float* pa = X + (size_t)(m0 + row) * 1024 + k0 + skg;
      f32x4 a0 = *(const f32x4*)pa;
      f32x4 a1 = *(const f32x4*)(pa + 4);
      bf16x8 pk;
      #pragma unroll
      for (int e = 0; e < 4; ++e) { pk[e] = f2bf(a0[e]); pk[e + 4] = f2bf(a1[e]); }
      *(bf16x8*)&As[row][skg] = pk;
      const float* pb = W + (size_t)(n0 + row) * 2048 + 1024 + k0 + skg;
      f32x4 b0 = *(const f32x4*)pb;
      f32x4 b1 = *(const f32x4*)(pb + 4);
      bf16x8 qk;
      #pragma unroll
      for (int e = 0; e < 4; ++e) { qk[e] = f2bf(b0[e]); qk[e + 4] = f2bf(b1[e]); }
      *(bf16x8*)&Bs[row][skg] = qk;
    }
    __syncthreads();
    bf16x8 af[4], bfv[4];
    #pragma unroll
    for (int mi = 0; mi < 4; ++mi) af[mi] = *(const bf16x8*)&As[wm + mi * 16 + jl][kq * 8];
    #pragma unroll
    for (int ni = 0; ni < 4; ++ni) bfv[ni] = *(const bf16x8*)&Bs[wn + ni * 16 + jl][kq * 8];
    #pragma unroll
    for (int mi = 0; mi < 4; ++mi)
      #pragma unroll
      for (int ni = 0; ni < 4; ++ni)
        acc[mi][ni] = __builtin_amdgcn_mfma_f32_16x16x32_bf16(af[mi], bfv[ni], acc[mi][ni], 0, 0, 0);
    __syncthreads();
  }
  #pragma unroll
  for (int ni = 0; ni < 4; ++ni) {
    int col = n0 + wn + ni * 16 + jl;
    float bv = bias[col];
    #pragma unroll
    for (int mi = 0; mi < 4; ++mi) {
      int rbase = m0 + wm + mi * 16 + kq * 4;
      #pragma unroll
      for (int r = 0; r < 4; ++r)
        C[(size_t)(rbase + r) * 1024 + col] = acc[mi][ni][r] + bv;
    }
  }
}

// ============================================================================
// Kernel 2: R3 structure (64 wgs = 2bg x 32cg, 8 waves K-split), tightened:
//   - agent-scope (sc1) exchange/flags
//   - ONE barrier/step: parity zred; publish via per-wave vmcnt drain + LDS
//     counter, 8th wave stores the flag
//   - padded zred, rcpf gates, xz prefetch, literal-offset A-loads
//   Safety: owner stores happen after B1, which joins all 8 waves whose polls
//   jointly cover all 32 same-bg producers at version >= t -> the parity-WAR
//   and zred-WAR arguments from R3 hold with a single barrier.
// ============================================================================
__global__ __launch_bounds__(512) void lstm_rec(
    const float* __restrict__ W, const float* __restrict__ h0,
    const float* __restrict__ c0, float* __restrict__ out,
    u16* __restrict__ exch, unsigned* __restrict__ flags) {
  __shared__ short Whs[32 * 1024];            // 64 KB bf16, XOR-swizzled
  __shared__ float zred[2][8][2][64][5];      // 40 KB, parity-dbuf, pad 5
  __shared__ unsigned pubcnt[2];
  const int tid  = threadIdx.x;
  const int lane = tid & 63, wave = tid >> 6;
  const int jl = lane & 15, kq = lane >> 4;
  const int bg = blockIdx.x >> 5;
  const int cg = blockIdx.x & 31;

  if (tid < 2) pubcnt[tid] = 0u;

  // --- stage Wh[32cg + j][k] -> LDS bf16, swizzled (R3-verified)
  {
    int j  = tid >> 4;
    int g0 = (tid & 15) * 8;
    const float* wrow = W + (size_t)(cg * 32 + j) * 2048;   // Wh = W[:, :1024]
    #pragma unroll
    for (int g = 0; g < 8; ++g) {
      int grp = g0 + g;
      const float* p = wrow + grp * 8;
      f32x4 a0 = *(const f32x4*)p;
      f32x4 a1 = *(const f32x4*)(p + 4);
      bf16x8 pk;
      #pragma unroll
      for (int e = 0; e < 4; ++e) { pk[e] = f2bf(a0[e]); pk[e + 4] = f2bf(a1[e]); }
      *(bf16x8*)&Whs[(j * 128 + (grp ^ (j & 7))) * 8] = pk;
    }
  }

  // --- owner thread (bp,cp); publish version 0 = bf16(h0) into parity 0
  const int bp  = tid >> 5;
  const int cp  = tid & 31;
  const int b   = bg * 16 + bp;
  const int col = cg * 32 + cp;
  float cst  = c0[b * 1024 + col];
  float hcur = 0.f;
  stg_coh_u16(exch + b * 1024 + col, (u16)f2bf(h0[b * 1024 + col]));
  __syncthreads();                            // Whs ready + h0 stores drained
  if (tid == 0)
    stg_coh_u32(flags + blockIdx.x * 16, 1u);

  // --- hoist B-fragments (constant across t)
  bf16x8 bfr[2][4];
  #pragma unroll
  for (int ct = 0; ct < 2; ++ct)
    #pragma unroll
    for (int kk = 0; kk < 4; ++kk) {
      int j2  = ct * 16 + jl;
      int grp = wave * 16 + kk * 4 + kq;
      bfr[ct][kk] = *(const bf16x8*)&Whs[(j2 * 128 + (grp ^ (j2 & 7))) * 8];
    }

  const int ct_o = cp >> 4;
  const int j16  = cp & 15;
  const int lred = ((bp >> 2) << 4) | j16;
  const int rred = bp & 3;
  const size_t obase = (size_t)b * (S_ * H_) + col;
  const u16* aptr = exch + (size_t)(bg * 16 + jl) * 1024 + wave * 128 + kq * 8;
  unsigned* myflag = flags + blockIdx.x * 16;
  const unsigned* fptr = flags + (((bg << 5) | (wave * 4 + (lane & 3))) * 16);

  float xz = out[obase];                      // xz for t=0

  for (int t = 0; t < S_; ++t) {
    const int p = t & 1;

    // ---- poll: this wave's 4 k-slice producers at version >= t
    if (lane < 4) {
      unsigned fv;
      for (;;) {
        asm volatile("global_load_dword %0, %1, off sc1"
                     : "=v"(fv) : "v"(fptr) : "memory");
        asm volatile("s_waitcnt vmcnt(0)" ::: "memory");
        if (__all(fv > (unsigned)t)) break;
      }
    }
    __builtin_amdgcn_sched_barrier(0);

    // ---- coherent bf16 A-frag loads (4 x 16B, literal offsets) + xz prefetch
    const u16* src = aptr + (size_t)p * EXN;
    bf16x8 afr[4];
#define LDA(K, OFF) asm volatile( \
    "global_load_dwordx4 %0, %1, off offset:" OFF " sc1" \
    : "=v"(afr[K]) : "v"(src) : "memory")
    LDA(0, "0"); LDA(1, "64"); LDA(2, "128"); LDA(3, "192");
#undef LDA
    float xz_next = out[obase + (size_t)(t + 1 < S_ ? t + 1 : t) * H_];
    asm volatile("s_waitcnt vmcnt(0)" ::: "memory");
    __builtin_amdgcn_sched_barrier(0);

    // ---- MFMA partials into parity zred
    #pragma unroll
    for (int ct = 0; ct < 2; ++ct) {
      f32x4 pacc = {0.f, 0.f, 0.f, 0.f};
      #pragma unroll
      for (int kk = 0; kk < 4; ++kk)
        pacc = __builtin_amdgcn_mfma_f32_16x16x32_bf16(afr[kk], bfr[ct][kk], pacc, 0, 0, 0);
      #pragma unroll
      for (int r = 0; r < 4; ++r)
        zred[p][wave][ct][lane][r] = pacc[r];
    }

    __syncthreads();   // B1: zred ready; joins all waves (=> all 32 producers >= t)

    // ---- owner: reduce 8 waves, gates (rcpf), publish
    float z = xz;
    #pragma unroll
    for (int w = 0; w < 8; ++w) z += zred[p][w][ct_o][lred][rred];
    float u  = __expf(-z);
    float u2 = u * u;
    float sg = __builtin_amdgcn_rcpf(1.f + u);                 // sigmoid(z)
    float tz = (1.f - u2) * __builtin_amdgcn_rcpf(1.f + u2);   // tanh(z)
    cst  = sg * (cst + tz);
    float v  = __expf(-2.f * cst);
    float tc = (1.f - v) * __builtin_amdgcn_rcpf(1.f + v);     // tanh(c)
    hcur = sg * tc;
    stg_coh_u16(exch + (size_t)(p ^ 1) * EXN + b * 1024 + col, (u16)f2bf(hcur));
    asm volatile("s_waitcnt vmcnt(0)" ::: "memory");   // this wave's stores acked
    if (lane == 0) {
      unsigned c8 = __hip_atomic_fetch_add(&pubcnt[p], 1u, __ATOMIC_RELAXED,
                                           __HIP_MEMORY_SCOPE_WORKGROUP);
      if (c8 == 7u) {                      // last wave: all 512 stores acked
        stg_coh_u32(myflag, (unsigned)(t + 2));
        __hip_atomic_store(&pubcnt[p], 0u, __ATOMIC_RELAXED,
                           __HIP_MEMORY_SCOPE_WORKGROUP);
      }
    }
    out[obase + (size_t)t * H_] = hcur;    // plain store, off the ack path
    xz = xz_next;
  }

  // ---- hn, cn
  const size_t OFS = (size_t)B_ * S_ * H_;
  out[OFS + b * 1024 + col] = hcur;
  out[OFS + (size_t)B_ * H_ + b * 1024 + col] = cst;
}

// ============================================================================
extern "C" void kernel_launch(void* const* d_in, const int* in_sizes, int n_in,
                              void* d_out, int out_size, void* d_ws, size_t ws_size,
                              hipStream_t stream) {
  const float* x    = (const float*)d_in[0];
  const float* h0   = (const float*)d_in[1];
  const float* c0   = (const float*)d_in[2];
  const float* W    = (const float*)d_in[3];
  const float* bias = (const float*)d_in[4];
  float* out = (float*)d_out;

  u16* exch = (u16*)d_ws;                               // 2 x 64 KB ping-pong
  unsigned* flags = (unsigned*)((char*)d_ws + 2 * EXN * sizeof(u16));
  hipMemsetAsync(flags, 0, NWG * 16 * sizeof(unsigned), stream);

  xz_gemm<<<dim3(8, 256), 256, 0, stream>>>(x, W, bias, out);
  lstm_rec<<<dim3(NWG), 512, 0, stream>>>(W, h0, c0, out, exch, flags);
}

// Round 9
// 2415.969 us; speedup vs baseline: 1.7547x; 1.2487x over previous
//
#include <hip/hip_runtime.h>

// Problem constants: B=32, S=1024, I=1024, H=1024, W is (H, I+H)
#define B_ 32
#define S_ 1024
#define H_ 1024
#define NWG 64            // 2 batch-groups x 32 col-groups
#define EXN (32 * 1024)   // u16 cells per parity buffer (32 batches x 1024 cols)

typedef float f32x4 __attribute__((ext_vector_type(4)));
typedef short bf16x8 __attribute__((ext_vector_type(8)));
typedef unsigned int u32x4 __attribute__((ext_vector_type(4)));
typedef unsigned short u16;

__device__ __forceinline__ short f2bf(float f) {
  union { float f; unsigned u; } v; v.f = f;
  unsigned r = v.u + 0x7FFFu + ((v.u >> 16) & 1u);
  return (short)(r >> 16);
}

__device__ __forceinline__ void stg_coh_u32(unsigned* p, unsigned v) {
  asm volatile("global_store_dword %0, %1, off sc0 sc1" :: "v"(p), "v"(v) : "memory");
}

// ============================================================================
// Kernel 1: xz GEMM (R1-verified, unchanged).
//   C[m][n] = sum_k x[m][k] * W[n][1024+k] + bias[n] -> d_out in-place.
// ============================================================================
__global__ __launch_bounds__(256) void xz_gemm(
    const float* __restrict__ X, const float* __restrict__ W,
    const float* __restrict__ bias, float* __restrict__ C) {
  __shared__ short As[128][40];
  __shared__ short Bs[128][40];
  const int tid  = threadIdx.x;
  const int lane = tid & 63, wave = tid >> 6;
  const int m0 = blockIdx.y * 128, n0 = blockIdx.x * 128;
  const int wm = (wave >> 1) * 64, wn = (wave & 1) * 64;
  const int jl = lane & 15, kq = lane >> 4;
  const int sr = tid >> 2, skg = (tid & 3) * 8;

  f32x4 zero4 = {0.f, 0.f, 0.f, 0.f};
  f32x4 acc[4][4];
  #pragma unroll
  for (int mi = 0; mi < 4; ++mi)
    #pragma unroll
    for (int ni = 0; ni < 4; ++ni) acc[mi][ni] = zero4;

  for (int k0 = 0; k0 < 1024; k0 += 32) {
    #pragma unroll
    for (int rr = 0; rr < 2; ++rr) {
      int row = sr + rr * 64;
      const float* pa = X + (size_t)(m0 + row) * 1024 + k0 + skg;
      f32x4 a0 = *(const f32x4*)pa;
      f32x4 a1 = *(const f32x4*)(pa + 4);
      bf16x8 pk;
      #pragma unroll
      for (int e = 0; e < 4; ++e) { pk[e] = f2bf(a0[e]); pk[e + 4] = f2bf(a1[e]); }
      *(bf16x8*)&As[row][skg] = pk;
      const float* pb = W + (size_t)(n0 + row) * 2048 + 1024 + k0 + skg;
      f32x4 b0 = *(const f32x4*)pb;
      f32x4 b1 = *(const f32x4*)(pb + 4);
      bf16x8 qk;
      #pragma unroll
      for (int e = 0; e < 4; ++e) { qk[e] = f2bf(b0[e]); qk[e + 4] = f2bf(b1[e]); }
      *(bf16x8*)&Bs[row][skg] = qk;
    }
    __syncthreads();
    bf16x8 af[4], bfv[4];
    #pragma unroll
    for (int mi = 0; mi < 4; ++mi) af[mi] = *(const bf16x8*)&As[wm + mi * 16 + jl][kq * 8];
    #pragma unroll
    for (int ni = 0; ni < 4; ++ni) bfv[ni] = *(const bf16x8*)&Bs[wn + ni * 16 + jl][kq * 8];
    #pragma unroll
    for (int mi = 0; mi < 4; ++mi)
      #pragma unroll
      for (int ni = 0; ni < 4; ++ni)
        acc[mi][ni] = __builtin_amdgcn_mfma_f32_16x16x32_bf16(af[mi], bfv[ni], acc[mi][ni], 0, 0, 0);
    __syncthreads();
  }
  #pragma unroll
  for (int ni = 0; ni < 4; ++ni) {
    int col = n0 + wn + ni * 16 + jl;
    float bv = bias[col];
    #pragma unroll
    for (int mi = 0; mi < 4; ++mi) {
      int rbase = m0 + wm + mi * 16 + kq * 4;
      #pragma unroll
      for (int r = 0; r < 4; ++r)
        C[(size_t)(rbase + r) * 1024 + col] = acc[mi][ni][r] + bv;
    }
  }
}

// ============================================================================
// Kernel 2: recurrence, tagged-granule exchange + flag backstop.
//   64 wgs = 2bg x 32cg, 512 thr (8 waves, K-split 128/wave).
//   Exchange cell = bf16(h); col==7 (mod 8) carries tag ((v>>1)&1) in its
//   mantissa LSB; version v lives in parity buffer v&1. Producers butterfly
//   8 cells into one lane -> ONE 16B store (atomic granule). Consumers spin
//   on the data loads themselves (<=32 iters), falling back to the R3/R6
//   flag protocol (ack'd, proven) + one reload -> cannot hang.
//   WAR/ABA safety: wg publishes v+1 only post-barrier, i.e. after all 8 of
//   its waves consumed v; union of waves covers all 32 same-bg producers;
//   so v+2 never lands in a parity buffer before every consumer is done
//   with v, and at step t parity p holds exactly version t.
// ============================================================================
__global__ __launch_bounds__(512) void lstm_rec(
    const float* __restrict__ W, const float* __restrict__ h0,
    const float* __restrict__ c0, float* __restrict__ out,
    u16* __restrict__ exch, unsigned* __restrict__ flags) {
  __shared__ float zred[2][8][2][64][5];    // 40 KB, parity-dbuf, pad 5
  __shared__ unsigned pubcnt[2];
  const int tid  = threadIdx.x;
  const int lane = tid & 63, wave = tid >> 6;
  const int jl = lane & 15, kq = lane >> 4;
  const int bg = blockIdx.x >> 5;
  const int cg = blockIdx.x & 31;

  if (tid < 2) pubcnt[tid] = 0u;

  // --- owner thread (bp, cp) owns cell (b, col)
  const int bp  = tid >> 5;
  const int cp  = tid & 31;
  const int b   = bg * 16 + bp;
  const int col = cg * 32 + cp;
  float cst  = c0[b * 1024 + col];
  float hcur = h0[b * 1024 + col];

  // PUBLISH(h, ver): butterfly 8 lanes' u16 cells into one 16B granule,
  // tag in cell (col%8==7)'s LSB, single dwordx4 store to parity (ver&1).
  // NOTE R8 bug fix: granule address uses col (global), not cp (wg-local).
#define PUBLISH(HVAL, VER) do {                                               \
    unsigned hb = (unsigned)(u16)f2bf(HVAL);                                  \
    if ((cp & 7) == 7) hb = (hb & 0xFFFEu) | (((unsigned)(VER) >> 1) & 1u);   \
    unsigned ot = (unsigned)__shfl_xor((int)hb, 1);                           \
    unsigned v0 = (lane & 1) ? (ot | (hb << 16)) : (hb | (ot << 16));         \
    unsigned o2 = (unsigned)__shfl_xor((int)v0, 2);                           \
    unsigned w0 = (lane & 2) ? o2 : v0;                                       \
    unsigned w1 = (lane & 2) ? v0 : o2;                                       \
    unsigned o0 = (unsigned)__shfl_xor((int)w0, 4);                           \
    unsigned o1 = (unsigned)__shfl_xor((int)w1, 4);                           \
    u32x4 g;                                                                  \
    g[0] = (lane & 4) ? o0 : w0;  g[1] = (lane & 4) ? o1 : w1;                \
    g[2] = (lane & 4) ? w0 : o0;  g[3] = (lane & 4) ? w1 : o1;                \
    if ((lane & 7) == 0) {                                                    \
      u16* dp = exch + (size_t)((VER) & 1) * EXN + b * 1024 + (col & ~7);     \
      asm volatile("global_store_dwordx4 %0, %1, off sc0 sc1"                 \
                   :: "v"(dp), "v"(g) : "memory");                            \
    }                                                                         \
  } while (0)

  PUBLISH(hcur, 0);                         // version 0 = h0 (granule path)

  // --- Wh fragments direct global -> registers (constant over t)
  bf16x8 bfr[2][4];
  #pragma unroll
  for (int ct = 0; ct < 2; ++ct)
    #pragma unroll
    for (int kk = 0; kk < 4; ++kk) {
      const float* pw = W + (size_t)(cg * 32 + ct * 16 + jl) * 2048
                          + wave * 128 + kk * 32 + kq * 8;   // Wh = W[:, :1024]
      f32x4 a0 = *(const f32x4*)pw;
      f32x4 a1 = *(const f32x4*)(pw + 4);
      bf16x8 pk;
      #pragma unroll
      for (int e = 0; e < 4; ++e) { pk[e] = f2bf(a0[e]); pk[e + 4] = f2bf(a1[e]); }
      bfr[ct][kk] = pk;
    }

  // prologue flag: version 0 acked for the fallback path
  asm volatile("s_waitcnt vmcnt(0)" ::: "memory");
  __syncthreads();
  unsigned* myflag = flags + blockIdx.x * 16;
  if (tid == 0) stg_coh_u32(myflag, 1u);

  const int ct_o = cp >> 4;
  const int lred = ((bp >> 2) << 4) | (cp & 15);
  const int rred = bp & 3;
  const size_t obase = (size_t)b * (S_ * H_) + col;
  const u16* aB = exch + (size_t)(bg * 16 + jl) * 1024 + wave * 128 + kq * 8;
  const unsigned* fptr = flags + (((bg << 5) | (wave * 4 + (lane & 3))) * 16);

  float xz = out[obase];                    // xz for t=0

  for (int t = 0; t < S_; ++t) {
    const int p = t & 1;
    const unsigned etg = (unsigned)((t >> 1) & 1);
    const u16* src = aB + (size_t)p * EXN;

    // ---- FAST: bounded spin on self-validating granule loads
    u32x4 L0, L1, L2, L3;
#define LDG4() do {                                                            \
    asm volatile("global_load_dwordx4 %0, %1, off sc0 sc1"                     \
                 : "=v"(L0) : "v"(src) : "memory");                            \
    asm volatile("global_load_dwordx4 %0, %1, off offset:64 sc0 sc1"           \
                 : "=v"(L1) : "v"(src) : "memory");                            \
    asm volatile("global_load_dwordx4 %0, %1, off offset:128 sc0 sc1"          \
                 : "=v"(L2) : "v"(src) : "memory");                            \
    asm volatile("global_load_dwordx4 %0, %1, off offset:192 sc0 sc1"          \
                 : "=v"(L3) : "v"(src) : "memory");                            \
    asm volatile("s_waitcnt vmcnt(0)" ::: "memory");                           \
    __builtin_amdgcn_sched_barrier(0);                                         \
  } while (0)

    bool ok = false;
    for (int it = 0; it < 32; ++it) {
      LDG4();
      unsigned bad = ((L0[3] >> 16) ^ etg) | ((L1[3] >> 16) ^ etg)
                   | ((L2[3] >> 16) ^ etg) | ((L3[3] >> 16) ^ etg);
      if (__all((bad & 1u) == 0u)) { ok = true; break; }
    }
    if (!ok) {
      // ---- SLOW backstop (R3-proven): flag poll, then one stable reload
      if (lane < 4) {
        unsigned fv;
        for (;;) {
          asm volatile("global_load_dword %0, %1, off sc0 sc1"
                       : "=v"(fv) : "v"(fptr) : "memory");
          asm volatile("s_waitcnt vmcnt(0)" ::: "memory");
          if (__all(fv > (unsigned)t)) break;
          __builtin_amdgcn_s_sleep(1);
        }
      }
      __builtin_amdgcn_sched_barrier(0);
      LDG4();
    }
#undef LDG4

    // ---- MFMA partials into parity zred (granules ARE the A-fragments)
    union { u32x4 u; bf16x8 h; } q0, q1, q2, q3;
    q0.u = L0; q1.u = L1; q2.u = L2; q3.u = L3;
    bf16x8 afr[4] = {q0.h, q1.h, q2.h, q3.h};
    #pragma unroll
    for (int ct = 0; ct < 2; ++ct) {
      f32x4 pacc = {0.f, 0.f, 0.f, 0.f};
      #pragma unroll
      for (int kk = 0; kk < 4; ++kk)
        pacc = __builtin_amdgcn_mfma_f32_16x16x32_bf16(afr[kk], bfr[ct][kk], pacc, 0, 0, 0);
      #pragma unroll
      for (int r = 0; r < 4; ++r)
        zred[p][wave][ct][lane][r] = pacc[r];
    }

    __syncthreads();   // the ONLY barrier per step

    // ---- owner: reduce 8 waves, gates (rcpf), publish v = t+1
    float z = xz;
    #pragma unroll
    for (int w = 0; w < 8; ++w) z += zred[p][w][ct_o][lred][rred];
    float u  = __expf(-z);
    float u2 = u * u;
    float sg = __builtin_amdgcn_rcpf(1.f + u);                 // sigmoid(z)
    float tz = (1.f - u2) * __builtin_amdgcn_rcpf(1.f + u2);   // tanh(z)
    cst  = sg * (cst + tz);
    float v  = __expf(-2.f * cst);
    float tc = (1.f - v) * __builtin_amdgcn_rcpf(1.f + v);     // tanh(c)
    hcur = sg * tc;

    PUBLISH(hcur, t + 1);                   // fast path: fire-and-forget

    // backstop flag (off the consumer fast path): ack granule, count waves
    asm volatile("s_waitcnt vmcnt(0)" ::: "memory");
    if (lane == 0) {
      unsigned c8 = __hip_atomic_fetch_add(&pubcnt[p], 1u, __ATOMIC_RELAXED,
                                           __HIP_MEMORY_SCOPE_WORKGROUP);
      if (c8 == 7u) {
        stg_coh_u32(myflag, (unsigned)(t + 2));
        __hip_atomic_store(&pubcnt[p], 0u, __ATOMIC_RELAXED,
                           __HIP_MEMORY_SCOPE_WORKGROUP);
      }
    }

    // off the critical path: fp32 output + next xz prefetch
    out[obase + (size_t)t * H_] = hcur;
    xz = out[obase + (size_t)(t + 1 < S_ ? t + 1 : t) * H_];
  }
#undef PUBLISH

  // ---- hn, cn
  const size_t OFS = (size_t)B_ * S_ * H_;
  out[OFS + b * 1024 + col] = hcur;
  out[OFS + (size_t)B_ * H_ + b * 1024 + col] = cst;
}

// ============================================================================
extern "C" void kernel_launch(void* const* d_in, const int* in_sizes, int n_in,
                              void* d_out, int out_size, void* d_ws, size_t ws_size,
                              hipStream_t stream) {
  const float* x    = (const float*)d_in[0];
  const float* h0   = (const float*)d_in[1];
  const float* c0   = (const float*)d_in[2];
  const float* W    = (const float*)d_in[3];
  const float* bias = (const float*)d_in[4];
  float* out = (float*)d_out;

  u16* exch = (u16*)d_ws;   // 2 x 64 KB ping-pong, bf16 cells w/ LSB tags
  unsigned* flags = (unsigned*)((char*)d_ws + 2 * EXN * sizeof(u16));
  // 0xFF => every stale tag bit reads 1, mismatching the first expected tag
  // (0) in both parities; also kills cross-replay staleness.
  hipMemsetAsync(exch, 0xFF, 2 * EXN * sizeof(u16), stream);
  hipMemsetAsync(flags, 0, NWG * 16 * sizeof(unsigned), stream);

  xz_gemm<<<dim3(8, 256), 256, 0, stream>>>(x, W, bias, out);
  lstm_rec<<<dim3(NWG), 512, 0, stream>>>(W, h0, c0, out, exch, flags);
}